// Round 9
// baseline (319.123 us; speedup 1.0000x reference)
//
#include <hip/hip_runtime.h>
#include <hip/hip_bf16.h>
#include <math.h>

// B=1, T=16, C=320, H=16, W=16, HEADS=8, DIM_HEAD=40, NREG=1, L=4096, LK=4097
#define CDIM 320
#define LQ   4096
#define LKTX 4097
#define NH   8
#define DH   40
#define NWORDS 65
#define NSPLIT 8
#define CBROWS 4224   // 66*64: rows 4097..4159 zeroed by qkv; 4160+ prefetch slack

typedef __attribute__((ext_vector_type(8))) short short8;   // 8 bf16 (x32 frag)
typedef __attribute__((ext_vector_type(4))) short short4v;  // 4 bf16 (x16 frag)
typedef __attribute__((ext_vector_type(4))) float f32x4;    // MFMA C/D frag

// NOTE: no __has_builtin guard — aux-target builtins are invisible to
// __has_builtin in the HIP *host* pass but are still callable (R6 lesson).
#define MFMA16(a, b, c) __builtin_amdgcn_mfma_f32_16x16x16bf16_1k(a, b, c, 0, 0, 0)
#define MFMA32(a, b, c) __builtin_amdgcn_mfma_f32_16x16x32_bf16(a, b, c, 0, 0, 0)

// scale * log2(e) folded into Wq: QK^T lands in log2 domain -> exp2 softmax
#define QSCALE ((float)(0.15811388300841897 * 1.4426950408889634))

// ---------------------------------------------------------------------------
// K1 prep (one launch, independent parts):
//   blocks [0,16384):     mask_pack  (field-packed format)
//   blocks [16384,16704): build_ctx rows 1..4096 via LDS transpose
//   blocks [16704,17904): weight pack (Wt, Wot) + reg-token ctx row 0
// Packed word (per q, per kt): bit (16r + 4ct + quad) = visibility of ctx key
// kt*64 + 16ct + 4quad + r. Flash: bit (4ct+16(r&1)) of (word>>(quad+32(r>>1))).
// ---------------------------------------------------------------------------
__global__ __launch_bounds__(256) void prep(
    const float* __restrict__ feat, const float* __restrict__ reg,
    const float* __restrict__ Wq, const float* __restrict__ Wk,
    const float* __restrict__ Wv, const float* __restrict__ Wo,
    const int* __restrict__ mask, unsigned long long* __restrict__ packed,
    __hip_bfloat16* __restrict__ ctxb, __hip_bfloat16* __restrict__ Wt,
    __hip_bfloat16* __restrict__ Wot) {
    __shared__ float xs[64 * 65];
    int b = blockIdx.x, t = threadIdx.x;
    if (b < 16384) {
        int wid = b * 4 + (t >> 6);
        int j = t & 63;
        int q = wid >> 4, g = wid & 15;
        const uint4* m4 = (const uint4*)(mask + (size_t)q * 4096 + g * 256);
        uint4 mv = m4[j];
        unsigned long long b0 = __ballot(mv.x != 0);
        unsigned long long b1 = __ballot(mv.y != 0);
        unsigned long long b2 = __ballot(mv.z != 0);
        unsigned long long b3 = __ballot(mv.w != 0);
        unsigned long long carry =
            (g == 0) ? 1ull
                     : (unsigned long long)(mask[(size_t)q * 4096 + g * 256 - 1] != 0);
        unsigned long long b3s = (b3 << 1) | carry;
        if (j < 4) {
            int sh = j * 16;
            unsigned long long w = ((b3s >> sh) & 0xFFFFull) |
                                   (((b0 >> sh) & 0xFFFFull) << 16) |
                                   (((b1 >> sh) & 0xFFFFull) << 32) |
                                   (((b2 >> sh) & 0xFFFFull) << 48);
            packed[(size_t)q * NWORDS + g * 4 + j] = w;
        }
        if (j == 4 && g == 15) packed[(size_t)q * NWORDS + 64] = b3 >> 63;
    } else if (b < 16704) {
        int bb = b - 16384;
        int tt = bb & 15, cg = (bb >> 4) % 5, hg = (bb >> 4) / 5;
        int c0 = cg * 64, hw0 = hg * 64;
        int cl = t >> 6, hwl = t & 63;
#pragma unroll
        for (int i = 0; i < 16; i++) {
            int c = cl * 16 + i;
            xs[c * 65 + hwl] = feat[(size_t)(tt * CDIM + c0 + c) * 256 + hw0 + hwl];
        }
        __syncthreads();
        int cq = t >> 6;
        int row = tt * 256 + hw0 + hwl;
        short8 v0, v1;
#pragma unroll
        for (int j = 0; j < 8; j++) {
            __hip_bfloat16 b0 = __float2bfloat16(xs[(cq * 16 + j) * 65 + hwl]);
            __hip_bfloat16 b1 = __float2bfloat16(xs[(cq * 16 + 8 + j) * 65 + hwl]);
            v0[j] = *(short*)&b0;
            v1[j] = *(short*)&b1;
        }
        short* dst = (short*)ctxb + (size_t)(1 + row) * CDIM + c0 + cq * 16;
        *(short8*)dst = v0;
        *(short8*)(dst + 8) = v1;
    } else {
        int idx = (b - 16704) * 256 + t;
        if (idx < 960 * 320) {
            int n = idx / 320, k = idx % 320;
            float v;
            if (n < 320)      v = Wq[k * 320 + n] * QSCALE;
            else if (n < 640) v = Wk[k * 320 + (n - 320)];
            else              v = Wv[k * 320 + (n - 640)];
            Wt[n * 320 + k] = __float2bfloat16(v);
        }
        if (idx < 320 * 320) {
            int n = idx / 320, k = idx % 320;
            Wot[n * 320 + k] = __float2bfloat16(Wo[k * 320 + n]);
        }
        if (idx < 320) ctxb[idx] = __float2bfloat16(reg[idx]);
    }
}

// ---------------------------------------------------------------------------
// K2 qkv_gemm: Cb[rows x 960] = ctx[pad x 320] @ Wt^T, 64x128 tile, 4 waves.
//     Natural [m][n] bf16 epilogue (coalesced). Rows >=4097 -> zeros.
//     N-guards (n < 960): grid covers 1024 cols (R7 WAW-race lesson).
// ---------------------------------------------------------------------------
__global__ __launch_bounds__(256) void qkv_gemm(
    const __hip_bfloat16* __restrict__ Ab, const __hip_bfloat16* __restrict__ Btb,
    __hip_bfloat16* __restrict__ Cbo) {
    __shared__ short As[64 * 72];
    __shared__ short Bs[128 * 72];
    const short* A  = (const short*)Ab;
    const short* Bt = (const short*)Btb;
    int t = threadIdx.x;
    int wv = t >> 6, lane = t & 63, quad = lane >> 4, l16 = lane & 15;
    int m0 = blockIdx.y * 64, n0 = blockIdx.x * 128;

    f32x4 acc[8];
#pragma unroll
    for (int ct = 0; ct < 8; ct++)
#pragma unroll
        for (int r = 0; r < 4; r++) acc[ct][r] = 0.f;

    for (int k0 = 0; k0 < 320; k0 += 64) {
        uint4 av[2], bv[4];
#pragma unroll
        for (int i = 0; i < 2; i++) {
            int c = t + i * 256;
            int row = c >> 3, kc = (c & 7) * 8;
            av[i] = make_uint4(0, 0, 0, 0);
            if (m0 + row < LKTX)
                av[i] = *(const uint4*)(A + (size_t)(m0 + row) * 320 + k0 + kc);
        }
#pragma unroll
        for (int i = 0; i < 4; i++) {
            int c = t + i * 256;
            int row = c >> 3, kc = (c & 7) * 8;
            bv[i] = make_uint4(0, 0, 0, 0);
            if (n0 + row < 960)
                bv[i] = *(const uint4*)(Bt + (size_t)(n0 + row) * 320 + k0 + kc);
        }
        __syncthreads();
#pragma unroll
        for (int i = 0; i < 2; i++) {
            int c = t + i * 256;
            *(uint4*)&As[(c >> 3) * 72 + (c & 7) * 8] = av[i];
        }
#pragma unroll
        for (int i = 0; i < 4; i++) {
            int c = t + i * 256;
            *(uint4*)&Bs[(c >> 3) * 72 + (c & 7) * 8] = bv[i];
        }
        __syncthreads();
        short8 a0 = *(const short8*)&As[(wv * 16 + l16) * 72 + quad * 8];
        short8 a1 = *(const short8*)&As[(wv * 16 + l16) * 72 + 32 + quad * 8];
#pragma unroll
        for (int ct = 0; ct < 8; ct++) {
            short8 b0 = *(const short8*)&Bs[(ct * 16 + l16) * 72 + quad * 8];
            short8 b1 = *(const short8*)&Bs[(ct * 16 + l16) * 72 + 32 + quad * 8];
            acc[ct] = MFMA32(a0, b0, acc[ct]);
            acc[ct] = MFMA32(a1, b1, acc[ct]);
        }
        __syncthreads();
    }
#pragma unroll
    for (int ct = 0; ct < 8; ct++)
#pragma unroll
        for (int r = 0; r < 4; r++) {
            int m = m0 + wv * 16 + quad * 4 + r;
            int n = n0 + ct * 16 + l16;
            if (n < 960)
                Cbo[(size_t)m * 960 + n] = __float2bfloat16(acc[ct][r]);
        }
}

// ---------------------------------------------------------------------------
// K3 flash attention, S^T orientation, 64 q per wave (256 q per block).
//     All-x16 MFMA: QK = 3 chunks of k16 (d padded 40->48), PV direct from
//     register P^T frags. Double-buffered LDS, 1 barrier/iter.
//     Ks stride 72 (b128 writes, cols 40..47 zero); Vs stride 68 (write bank
//     step 16 -> ~2-way, reads uniform). l rides in V ones-row d=40.
// ---------------------------------------------------------------------------
__global__ __launch_bounds__(256, 3) void flash_attn(
    const __hip_bfloat16* __restrict__ Cbh,
    const unsigned long long* __restrict__ packed,
    float* __restrict__ Opart, float* __restrict__ l_arr) {
    __shared__ short Ks[2 * 64 * 72];   // [buf][key][d 0..47 used]
    __shared__ short Vs[2 * 48 * 68];   // [buf][d 0..47][key]; d40 = ones

    int t = threadIdx.x;
    int wv = t >> 6, lane = t & 63;
    int quad = lane >> 4, l16 = lane & 15;
    int h = blockIdx.y, s = blockIdx.z;
    int q0 = blockIdx.x * 256 + wv * 64;
    int kt0 = s ? 8 * s + 1 : 0;
    int nkt = s ? 8 : 9;
    const short* Cb = (const short*)Cbh;

    // one-time pad init (both buffers): Ks cols 40..47; Vs rows 40..47
    for (int i = t; i < 64 * 8; i += 256) {
        int rr = i >> 3, c = 40 + (i & 7);
        Ks[rr * 72 + c] = 0;
        Ks[64 * 72 + rr * 72 + c] = 0;
    }
    for (int i = t; i < 8 * 68; i += 256) {
        int rr = i / 68, c = i % 68;
        short v = (rr == 0 && c < 64) ? (short)0x3F80 : (short)0;
        Vs[(40 + rr) * 68 + c] = v;
        Vs[48 * 68 + (40 + rr) * 68 + c] = v;
    }

    // Q B-frags (4 q-sets): B[k=d=kc*16+quad*4+j][n=q=l16], d padded to 48
    short4v qb[4][3];
#pragma unroll
    for (int qs = 0; qs < 4; qs++) {
        const short* qp = Cb + (size_t)(q0 + qs * 16 + l16 + 1) * 960 + h * DH;
        qb[qs][0] = *(const short4v*)(qp + quad * 4);
        qb[qs][1] = *(const short4v*)(qp + 16 + quad * 4);
        short4v z = {0, 0, 0, 0};
        qb[qs][2] = (quad < 2) ? *(const short4v*)(qp + 32 + quad * 4) : z;
    }

    // staging decode: chunk (key, cc), chunk ids t and t+256 (<320)
    int key0 = t / 5, cc0 = t - 5 * key0;
    int t2 = t + 256;
    int key1 = t2 / 5, cc1 = t2 - 5 * key1;
    bool has2 = (t < 64);
    const short* pK0 = Cb + (size_t)(kt0 * 64 + key0) * 960 + 320 + h * DH + cc0 * 8;
    const short* pV0 = Cb + (size_t)(kt0 * 64 + key0) * 960 + 640 + h * DH + cc0 * 8;
    const short* pK1 = Cb + (size_t)(kt0 * 64 + key1) * 960 + 320 + h * DH + cc1 * 8;
    const short* pV1 = Cb + (size_t)(kt0 * 64 + key1) * 960 + 640 + h * DH + cc1 * 8;
    const unsigned long long* pM[4];
#pragma unroll
    for (int qs = 0; qs < 4; qs++)
        pM[qs] = packed + (size_t)(q0 + qs * 16 + l16) * NWORDS + kt0;

    // prefetch tile 0
    uint4 rk0 = *(const uint4*)pK0;  pK0 += 61440;
    uint4 rv0 = *(const uint4*)pV0;  pV0 += 61440;
    uint4 rk1 = make_uint4(0, 0, 0, 0), rv1 = make_uint4(0, 0, 0, 0);
    if (has2) { rk1 = *(const uint4*)pK1; rv1 = *(const uint4*)pV1; }
    pK1 += 61440; pV1 += 61440;
    unsigned long long wq[4];
#pragma unroll
    for (int qs = 0; qs < 4; qs++) wq[qs] = *pM[qs]++;

    f32x4 accO[4][3];
#pragma unroll
    for (int qs = 0; qs < 4; qs++)
#pragma unroll
        for (int dt = 0; dt < 3; dt++)
#pragma unroll
            for (int r = 0; r < 4; r++) accO[qs][dt][r] = 0.f;

    for (int it = 0; it < nkt; it++) {
        int ko = (it & 1) * (64 * 72), vo = (it & 1) * (48 * 68);
        // write staged regs -> current buffer
        *(uint4*)&Ks[ko + key0 * 72 + cc0 * 8] = rk0;
        {
            const short* ds = (const short*)&rv0;
#pragma unroll
            for (int u = 0; u < 8; u++) Vs[vo + (cc0 * 8 + u) * 68 + key0] = ds[u];
        }
        if (has2) {
            *(uint4*)&Ks[ko + key1 * 72 + cc1 * 8] = rk1;
            const short* ds = (const short*)&rv1;
#pragma unroll
            for (int u = 0; u < 8; u++) Vs[vo + (cc1 * 8 + u) * 68 + key1] = ds[u];
        }
        unsigned long long mw[4];
#pragma unroll
        for (int qs = 0; qs < 4; qs++) mw[qs] = wq[qs];
        // prefetch next tile (in flight across barrier)
        rk0 = *(const uint4*)pK0;  pK0 += 61440;
        rv0 = *(const uint4*)pV0;  pV0 += 61440;
        if (has2) { rk1 = *(const uint4*)pK1; rv1 = *(const uint4*)pV1; }
        pK1 += 61440; pV1 += 61440;
#pragma unroll
        for (int qs = 0; qs < 4; qs++) wq[qs] = *pM[qs]++;
        __syncthreads();

        const short* KB = &Ks[ko];
        const short* VB = &Vs[vo];
        unsigned lo[4], hi[4];
#pragma unroll
        for (int qs = 0; qs < 4; qs++) {
            lo[qs] = (unsigned)(mw[qs] >> quad);
            hi[qs] = (unsigned)(mw[qs] >> (quad + 32));
        }

#pragma unroll
        for (int ct = 0; ct < 4; ct++) {
            // QK^T (S^T): A=K frag, B=Q frag, 3 k16 chunks
            f32x4 S[4];
#pragma unroll
            for (int qs = 0; qs < 4; qs++) S[qs] = f32x4{0.f, 0.f, 0.f, 0.f};
#pragma unroll
            for (int kc = 0; kc < 3; kc++) {
                short4v kf = *(const short4v*)&KB[(ct * 16 + l16) * 72 + kc * 16 + quad * 4];
#pragma unroll
                for (int qs = 0; qs < 4; qs++)
                    S[qs] = MFMA16(kf, qb[qs][kc], S[qs]);
            }
            // softmax (m == 0): p = exp2(s) * maskbit -> P^T register frag
            short4v pf[4];
#pragma unroll
            for (int qs = 0; qs < 4; qs++) {
                float p0 = __builtin_amdgcn_exp2f(S[qs][0]);
                float p1 = __builtin_amdgcn_exp2f(S[qs][1]);
                float p2 = __builtin_amdgcn_exp2f(S[qs][2]);
                float p3 = __builtin_amdgcn_exp2f(S[qs][3]);
                p0 = ((lo[qs] >> (4 * ct)) & 1u) ? p0 : 0.f;
                p1 = ((lo[qs] >> (4 * ct + 16)) & 1u) ? p1 : 0.f;
                p2 = ((hi[qs] >> (4 * ct)) & 1u) ? p2 : 0.f;
                p3 = ((hi[qs] >> (4 * ct + 16)) & 1u) ? p3 : 0.f;
                unsigned u0 = __float_as_uint(p0) + 0x8000u;
                unsigned u1 = __float_as_uint(p1) + 0x8000u;
                unsigned u2 = __float_as_uint(p2) + 0x8000u;
                unsigned u3 = __float_as_uint(p3) + 0x8000u;
                uint2 pk = make_uint2((u0 >> 16) | (u1 & 0xFFFF0000u),
                                      (u2 >> 16) | (u3 & 0xFFFF0000u));
                pf[qs] = *(short4v*)&pk;
            }
            // PV: O^T[d][q] += V^T . P^T (x16, P from registers)
#pragma unroll
            for (int dt = 0; dt < 3; dt++) {
                short4v vf = *(const short4v*)&VB[(dt * 16 + l16) * 68 + ct * 16 + quad * 4];
#pragma unroll
                for (int qs = 0; qs < 4; qs++)
                    accO[qs][dt] = MFMA16(vf, pf[qs], accO[qs][dt]);
            }
        }
    }

    // epilogue: unnormalized O (row=d=dt*16+quad*4+r, col=q=l16) + l (d=40)
#pragma unroll
    for (int qs = 0; qs < 4; qs++) {
        int q = q0 + qs * 16 + l16;
        size_t base = ((size_t)(s * NH + h) * LQ + q) * DH;
        float4 f0 = make_float4(accO[qs][0][0], accO[qs][0][1], accO[qs][0][2], accO[qs][0][3]);
        float4 f1 = make_float4(accO[qs][1][0], accO[qs][1][1], accO[qs][1][2], accO[qs][1][3]);
        *(float4*)&Opart[base + quad * 4] = f0;
        *(float4*)&Opart[base + 16 + quad * 4] = f1;
        if (quad < 2) {
            float4 f2 = make_float4(accO[qs][2][0], accO[qs][2][1], accO[qs][2][2], accO[qs][2][3]);
            *(float4*)&Opart[base + 32 + quad * 4] = f2;
        }
        if (quad == 2) l_arr[(size_t)(s * NH + h) * LQ + q] = accO[qs][2][0];
    }
}

// ---------------------------------------------------------------------------
// K4 combine: aob[q][h*40+d] = (sum_s Opart) / (sum_s l), bf16
// ---------------------------------------------------------------------------
__global__ __launch_bounds__(256) void combine(
    const float* __restrict__ Opart, const float* __restrict__ l_arr,
    __hip_bfloat16* __restrict__ aob) {
    int idx = blockIdx.x * 256 + threadIdx.x;   // ((h*4096+q)*5 + dgroup)
    if (idx >= NH * LQ * 5) return;
    int dg = idx % 5;
    int hq = idx / 5;
    int q = hq & (LQ - 1), h = hq >> 12;
    float ls = 0.f;
    float vals[8] = {0, 0, 0, 0, 0, 0, 0, 0};
#pragma unroll
    for (int sp = 0; sp < NSPLIT; sp++) {
        size_t rbase = ((size_t)(sp * NH + h) * LQ + q) * DH + dg * 8;
        float4 a = *(const float4*)&Opart[rbase];
        float4 b = *(const float4*)&Opart[rbase + 4];
        vals[0] += a.x; vals[1] += a.y; vals[2] += a.z; vals[3] += a.w;
        vals[4] += b.x; vals[5] += b.y; vals[6] += b.z; vals[7] += b.w;
        ls += l_arr[(size_t)(sp * NH + h) * LQ + q];
    }
    float inv = 1.f / ls;
    short8 o;
#pragma unroll
    for (int j = 0; j < 8; j++) {
        unsigned u = __float_as_uint(vals[j] * inv) + 0x8000u;
        o[j] = (short)(u >> 16);
    }
    *(short8*)((short*)aob + (size_t)q * CDIM + h * DH + dg * 8) = o;
}

// ---------------------------------------------------------------------------
// K5 out_gemm: out[perm(m)] = aob @ Wot^T + bo (64x64 tile, 4 waves)
// ---------------------------------------------------------------------------
__global__ __launch_bounds__(256) void out_gemm(
    const __hip_bfloat16* __restrict__ Ab, const __hip_bfloat16* __restrict__ Btb,
    float* __restrict__ C, const float* __restrict__ bias) {
    __shared__ short As[64 * 72];
    __shared__ short Bs[64 * 72];
    const short* A  = (const short*)Ab;
    const short* Bt = (const short*)Btb;
    int t = threadIdx.x;
    int wv = t >> 6, lane = t & 63, quad = lane >> 4, l16 = lane & 15;
    int m0 = blockIdx.y * 64, n0 = blockIdx.x * 64;

    f32x4 acc[4];
#pragma unroll
    for (int ct = 0; ct < 4; ct++)
#pragma unroll
        for (int r = 0; r < 4; r++) acc[ct][r] = 0.f;

    for (int k0 = 0; k0 < 320; k0 += 64) {
        uint4 av[2], bv[2];
#pragma unroll
        for (int i = 0; i < 2; i++) {
            int c = t + i * 256;
            int row = c >> 3, kc = (c & 7) * 8;
            av[i] = *(const uint4*)(A + (size_t)(m0 + row) * 320 + k0 + kc);
            bv[i] = *(const uint4*)(Bt + (size_t)(n0 + row) * 320 + k0 + kc);
        }
        __syncthreads();
#pragma unroll
        for (int i = 0; i < 2; i++) {
            int c = t + i * 256;
            *(uint4*)&As[(c >> 3) * 72 + (c & 7) * 8] = av[i];
            *(uint4*)&Bs[(c >> 3) * 72 + (c & 7) * 8] = bv[i];
        }
        __syncthreads();
        short8 a0 = *(const short8*)&As[(wv * 16 + l16) * 72 + quad * 8];
        short8 a1 = *(const short8*)&As[(wv * 16 + l16) * 72 + 32 + quad * 8];
#pragma unroll
        for (int ct = 0; ct < 4; ct++) {
            short8 b0 = *(const short8*)&Bs[(ct * 16 + l16) * 72 + quad * 8];
            short8 b1 = *(const short8*)&Bs[(ct * 16 + l16) * 72 + 32 + quad * 8];
            acc[ct] = MFMA32(a0, b0, acc[ct]);
            acc[ct] = MFMA32(a1, b1, acc[ct]);
        }
        __syncthreads();
    }
#pragma unroll
    for (int ct = 0; ct < 4; ct++)
#pragma unroll
        for (int r = 0; r < 4; r++) {
            int m = m0 + wv * 16 + quad * 4 + r;
            int n = n0 + ct * 16 + l16;
            int rp = (m & 255) * 16 + (m >> 8);
            C[(size_t)rp * CDIM + n] = acc[ct][r] + bias[n];
        }
}

// ---------------------------------------------------------------------------
// kernel_launch (5 launches: prep -> qkv -> flash -> combine -> out)
// ---------------------------------------------------------------------------
extern "C" void kernel_launch(void* const* d_in, const int* in_sizes, int n_in,
                              void* d_out, int out_size, void* d_ws, size_t ws_size,
                              hipStream_t stream) {
    const float* feat = (const float*)d_in[0];
    const int*   mask = (const int*)d_in[1];
    const float* Wq   = (const float*)d_in[2];
    const float* Wk   = (const float*)d_in[3];
    const float* Wv   = (const float*)d_in[4];
    const float* reg  = (const float*)d_in[5];
    const float* Wo   = (const float*)d_in[6];
    const float* bo   = (const float*)d_in[7];
    float* out = (float*)d_out;

    char* p = (char*)d_ws;
    auto alloc = [&](size_t bytes) {
        char* r = p;
        p += (bytes + 255) & ~(size_t)255;
        return r;
    };
    __hip_bfloat16* ctxb = (__hip_bfloat16*)alloc((size_t)LKTX * CDIM * 2);
    __hip_bfloat16* Cb   = (__hip_bfloat16*)alloc((size_t)CBROWS * 960 * 2);
    __hip_bfloat16* Wt   = (__hip_bfloat16*)alloc((size_t)960 * 320 * 2);
    __hip_bfloat16* Wot  = (__hip_bfloat16*)alloc((size_t)320 * 320 * 2);
    unsigned long long* packed =
        (unsigned long long*)alloc(((size_t)LQ * NWORDS + 64) * 8);
    float* Opart = (float*)alloc((size_t)NSPLIT * NH * LQ * DH * 4);
    float* l_arr = (float*)alloc((size_t)NSPLIT * NH * LQ * 4);
    __hip_bfloat16* aob  = (__hip_bfloat16*)alloc((size_t)LQ * CDIM * 2);

    prep<<<17904, 256, 0, stream>>>(feat, reg, Wq, Wk, Wv, Wo, mask, packed,
                                    ctxb, Wt, Wot);
    qkv_gemm<<<dim3(8, 65), 256, 0, stream>>>(ctxb, Wt, Cb);
    flash_attn<<<dim3(16, NH, NSPLIT), 256, 0, stream>>>(Cb, packed, Opart, l_arr);
    combine<<<(NH * LQ * 5 + 255) / 256, 256, 0, stream>>>(Opart, l_arr, aob);
    out_gemm<<<dim3(5, 64), 256, 0, stream>>>(aob, Wot, out, bo);
}

// Round 10
// 194.235 us; speedup vs baseline: 1.6430x; 1.6430x over previous
//
#include <hip/hip_runtime.h>
#include <hip/hip_bf16.h>
#include <math.h>

// B=1, T=16, C=320, H=16, W=16, HEADS=8, DIM_HEAD=40, NREG=1, L=4096, LK=4097
#define CDIM 320
#define LQ   4096
#define LKTX 4097
#define NH   8
#define DH   40
#define NWORDS 65
#define NSPLIT 4
#define CBROWS 4224   // 66*64: rows 4097..4159 zeroed by qkv; 4160+ prefetch slack

typedef __attribute__((ext_vector_type(8))) short short8;   // 8 bf16 (x32 frag)
typedef __attribute__((ext_vector_type(4))) short short4v;  // 4 bf16 (x16 frag)
typedef __attribute__((ext_vector_type(4))) float f32x4;    // MFMA C/D frag

// NOTE: no __has_builtin guard — aux-target builtins are invisible to
// __has_builtin in the HIP *host* pass but are still callable (R6 lesson).
#define MFMA16(a, b, c) __builtin_amdgcn_mfma_f32_16x16x16bf16_1k(a, b, c, 0, 0, 0)
#define MFMA32(a, b, c) __builtin_amdgcn_mfma_f32_16x16x32_bf16(a, b, c, 0, 0, 0)

// scale * log2(e) folded into Wq: QK^T lands in log2 domain -> exp2 softmax
#define QSCALE ((float)(0.15811388300841897 * 1.4426950408889634))

// ---------------------------------------------------------------------------
// K1 prep (one launch, independent parts):
//   blocks [0,16384):     mask_pack  (field-packed format)
//   blocks [16384,16704): build_ctx rows 1..4096 via LDS transpose
//   blocks [16704,17904): weight pack (Wt, Wot) + reg-token ctx row 0
// Packed word (per q, per kt): bit (16r + 4ct + quad) = visibility of ctx key
// kt*64 + 16ct + 4quad + r. Flash: bit (4ct+16(r&1)) of (word>>(quad+32(r>>1))).
// ---------------------------------------------------------------------------
__global__ __launch_bounds__(256) void prep(
    const float* __restrict__ feat, const float* __restrict__ reg,
    const float* __restrict__ Wq, const float* __restrict__ Wk,
    const float* __restrict__ Wv, const float* __restrict__ Wo,
    const int* __restrict__ mask, unsigned long long* __restrict__ packed,
    __hip_bfloat16* __restrict__ ctxb, __hip_bfloat16* __restrict__ Wt,
    __hip_bfloat16* __restrict__ Wot) {
    __shared__ float xs[64 * 65];
    int b = blockIdx.x, t = threadIdx.x;
    if (b < 16384) {
        int wid = b * 4 + (t >> 6);
        int j = t & 63;
        int q = wid >> 4, g = wid & 15;
        const uint4* m4 = (const uint4*)(mask + (size_t)q * 4096 + g * 256);
        uint4 mv = m4[j];
        unsigned long long b0 = __ballot(mv.x != 0);
        unsigned long long b1 = __ballot(mv.y != 0);
        unsigned long long b2 = __ballot(mv.z != 0);
        unsigned long long b3 = __ballot(mv.w != 0);
        unsigned long long carry =
            (g == 0) ? 1ull
                     : (unsigned long long)(mask[(size_t)q * 4096 + g * 256 - 1] != 0);
        unsigned long long b3s = (b3 << 1) | carry;
        if (j < 4) {
            int sh = j * 16;
            unsigned long long w = ((b3s >> sh) & 0xFFFFull) |
                                   (((b0 >> sh) & 0xFFFFull) << 16) |
                                   (((b1 >> sh) & 0xFFFFull) << 32) |
                                   (((b2 >> sh) & 0xFFFFull) << 48);
            packed[(size_t)q * NWORDS + g * 4 + j] = w;
        }
        if (j == 4 && g == 15) packed[(size_t)q * NWORDS + 64] = b3 >> 63;
    } else if (b < 16704) {
        int bb = b - 16384;
        int tt = bb & 15, cg = (bb >> 4) % 5, hg = (bb >> 4) / 5;
        int c0 = cg * 64, hw0 = hg * 64;
        int cl = t >> 6, hwl = t & 63;
#pragma unroll
        for (int i = 0; i < 16; i++) {
            int c = cl * 16 + i;
            xs[c * 65 + hwl] = feat[(size_t)(tt * CDIM + c0 + c) * 256 + hw0 + hwl];
        }
        __syncthreads();
        int cq = t >> 6;
        int row = tt * 256 + hw0 + hwl;
        short8 v0, v1;
#pragma unroll
        for (int j = 0; j < 8; j++) {
            __hip_bfloat16 b0 = __float2bfloat16(xs[(cq * 16 + j) * 65 + hwl]);
            __hip_bfloat16 b1 = __float2bfloat16(xs[(cq * 16 + 8 + j) * 65 + hwl]);
            v0[j] = *(short*)&b0;
            v1[j] = *(short*)&b1;
        }
        short* dst = (short*)ctxb + (size_t)(1 + row) * CDIM + c0 + cq * 16;
        *(short8*)dst = v0;
        *(short8*)(dst + 8) = v1;
    } else {
        int idx = (b - 16704) * 256 + t;
        if (idx < 960 * 320) {
            int n = idx / 320, k = idx % 320;
            float v;
            if (n < 320)      v = Wq[k * 320 + n] * QSCALE;
            else if (n < 640) v = Wk[k * 320 + (n - 320)];
            else              v = Wv[k * 320 + (n - 640)];
            Wt[n * 320 + k] = __float2bfloat16(v);
        }
        if (idx < 320 * 320) {
            int n = idx / 320, k = idx % 320;
            Wot[n * 320 + k] = __float2bfloat16(Wo[k * 320 + n]);
        }
        if (idx < 320) ctxb[idx] = __float2bfloat16(reg[idx]);
    }
}

// ---------------------------------------------------------------------------
// K2 qkv_gemm: Cb[rows x 960] = ctx[pad x 320] @ Wt^T, 64x128 tile, 4 waves.
//     Natural [m][n] bf16 epilogue (coalesced). Rows >=4097 -> zeros.
//     N-guards (n < 960): grid covers 1024 cols (R7 WAW-race lesson).
// ---------------------------------------------------------------------------
__global__ __launch_bounds__(256) void qkv_gemm(
    const __hip_bfloat16* __restrict__ Ab, const __hip_bfloat16* __restrict__ Btb,
    __hip_bfloat16* __restrict__ Cbo) {
    __shared__ short As[64 * 72];
    __shared__ short Bs[128 * 72];
    const short* A  = (const short*)Ab;
    const short* Bt = (const short*)Btb;
    int t = threadIdx.x;
    int wv = t >> 6, lane = t & 63, quad = lane >> 4, l16 = lane & 15;
    int m0 = blockIdx.y * 64, n0 = blockIdx.x * 128;

    f32x4 acc[8];
#pragma unroll
    for (int ct = 0; ct < 8; ct++)
#pragma unroll
        for (int r = 0; r < 4; r++) acc[ct][r] = 0.f;

    for (int k0 = 0; k0 < 320; k0 += 64) {
        uint4 av[2], bv[4];
#pragma unroll
        for (int i = 0; i < 2; i++) {
            int c = t + i * 256;
            int row = c >> 3, kc = (c & 7) * 8;
            av[i] = make_uint4(0, 0, 0, 0);
            if (m0 + row < LKTX)
                av[i] = *(const uint4*)(A + (size_t)(m0 + row) * 320 + k0 + kc);
        }
#pragma unroll
        for (int i = 0; i < 4; i++) {
            int c = t + i * 256;
            int row = c >> 3, kc = (c & 7) * 8;
            bv[i] = make_uint4(0, 0, 0, 0);
            if (n0 + row < 960)
                bv[i] = *(const uint4*)(Bt + (size_t)(n0 + row) * 320 + k0 + kc);
        }
        __syncthreads();
#pragma unroll
        for (int i = 0; i < 2; i++) {
            int c = t + i * 256;
            *(uint4*)&As[(c >> 3) * 72 + (c & 7) * 8] = av[i];
        }
#pragma unroll
        for (int i = 0; i < 4; i++) {
            int c = t + i * 256;
            *(uint4*)&Bs[(c >> 3) * 72 + (c & 7) * 8] = bv[i];
        }
        __syncthreads();
        short8 a0 = *(const short8*)&As[(wv * 16 + l16) * 72 + quad * 8];
        short8 a1 = *(const short8*)&As[(wv * 16 + l16) * 72 + 32 + quad * 8];
#pragma unroll
        for (int ct = 0; ct < 8; ct++) {
            short8 b0 = *(const short8*)&Bs[(ct * 16 + l16) * 72 + quad * 8];
            short8 b1 = *(const short8*)&Bs[(ct * 16 + l16) * 72 + 32 + quad * 8];
            acc[ct] = MFMA32(a0, b0, acc[ct]);
            acc[ct] = MFMA32(a1, b1, acc[ct]);
        }
        __syncthreads();
    }
#pragma unroll
    for (int ct = 0; ct < 8; ct++)
#pragma unroll
        for (int r = 0; r < 4; r++) {
            int m = m0 + wv * 16 + quad * 4 + r;
            int n = n0 + ct * 16 + l16;
            if (n < 960)
                Cbo[(size_t)m * 960 + n] = __float2bfloat16(acc[ct][r]);
        }
}

// ---------------------------------------------------------------------------
// K3 flash attention (R8 macro-shape + verified micro-fixes).
//     Block = 1 head x 128 q x 1 split, 4 waves x 32 q (2 q-sets of 16).
//     All-x16 QK (3 chunks of k16, d padded 40->48); PV direct from register
//     P^T frags. Double-buffered LDS, 1 barrier/iter. Vs stride 68 (staging
//     write bank step 16 -> ~2-way). l rides in V ones-row d=40.
// ---------------------------------------------------------------------------
__global__ __launch_bounds__(256, 4) void flash_attn(
    const __hip_bfloat16* __restrict__ Cbh,
    const unsigned long long* __restrict__ packed,
    float* __restrict__ Opart, float* __restrict__ l_arr) {
    __shared__ short Ks[2 * 64 * 72];   // [buf][key][d 0..47 used]
    __shared__ short Vs[2 * 48 * 68];   // [buf][d 0..47][key]; d40 = ones

    int t = threadIdx.x;
    int wv = t >> 6, lane = t & 63;
    int quad = lane >> 4, l16 = lane & 15;
    int h = blockIdx.y, s = blockIdx.z;
    int q0 = blockIdx.x * 128 + wv * 32;
    int kt0 = (s == 0) ? 0 : 16 * s + 1;
    int nkt = s ? 16 : 17;
    const short* Cb = (const short*)Cbh;

    // one-time pad init (both buffers): Ks cols 40..47; Vs rows 40..47
    for (int i = t; i < 64 * 8; i += 256) {
        int rr = i >> 3, c = 40 + (i & 7);
        Ks[rr * 72 + c] = 0;
        Ks[64 * 72 + rr * 72 + c] = 0;
    }
    for (int i = t; i < 8 * 68; i += 256) {
        int rr = i / 68, c = i % 68;
        short v = (rr == 0 && c < 64) ? (short)0x3F80 : (short)0;
        Vs[(40 + rr) * 68 + c] = v;
        Vs[48 * 68 + (40 + rr) * 68 + c] = v;
    }

    // Q B-frags (2 q-sets): B[k=d=kc*16+quad*4+j][n=q=l16], d padded to 48
    short4v qb[2][3];
#pragma unroll
    for (int qs = 0; qs < 2; qs++) {
        const short* qp = Cb + (size_t)(q0 + qs * 16 + l16 + 1) * 960 + h * DH;
        qb[qs][0] = *(const short4v*)(qp + quad * 4);
        qb[qs][1] = *(const short4v*)(qp + 16 + quad * 4);
        short4v z = {0, 0, 0, 0};
        qb[qs][2] = (quad < 2) ? *(const short4v*)(qp + 32 + quad * 4) : z;
    }

    // staging decode: chunk (key, cc), chunk ids t and t+256 (<320)
    int key0 = t / 5, cc0 = t - 5 * key0;
    int t2 = t + 256;
    int key1 = t2 / 5, cc1 = t2 - 5 * key1;
    bool has2 = (t < 64);
    const short* pK0 = Cb + (size_t)(kt0 * 64 + key0) * 960 + 320 + h * DH + cc0 * 8;
    const short* pV0 = Cb + (size_t)(kt0 * 64 + key0) * 960 + 640 + h * DH + cc0 * 8;
    const short* pK1 = Cb + (size_t)(kt0 * 64 + key1) * 960 + 320 + h * DH + cc1 * 8;
    const short* pV1 = Cb + (size_t)(kt0 * 64 + key1) * 960 + 640 + h * DH + cc1 * 8;
    const unsigned long long* pM0 = packed + (size_t)(q0 + l16) * NWORDS + kt0;
    const unsigned long long* pM1 = packed + (size_t)(q0 + 16 + l16) * NWORDS + kt0;

    // prefetch tile 0
    uint4 rk0 = *(const uint4*)pK0;  pK0 += 61440;
    uint4 rv0 = *(const uint4*)pV0;  pV0 += 61440;
    uint4 rk1 = make_uint4(0, 0, 0, 0), rv1 = make_uint4(0, 0, 0, 0);
    if (has2) { rk1 = *(const uint4*)pK1; rv1 = *(const uint4*)pV1; }
    pK1 += 61440; pV1 += 61440;
    unsigned long long wq0 = *pM0++;
    unsigned long long wq1 = *pM1++;

    f32x4 accO[2][3];
#pragma unroll
    for (int qs = 0; qs < 2; qs++)
#pragma unroll
        for (int dt = 0; dt < 3; dt++)
#pragma unroll
            for (int r = 0; r < 4; r++) accO[qs][dt][r] = 0.f;

    for (int it = 0; it < nkt; it++) {
        int ko = (it & 1) * (64 * 72), vo = (it & 1) * (48 * 68);
        // write staged regs -> current buffer
        *(uint4*)&Ks[ko + key0 * 72 + cc0 * 8] = rk0;
        {
            const short* ds = (const short*)&rv0;
#pragma unroll
            for (int u = 0; u < 8; u++) Vs[vo + (cc0 * 8 + u) * 68 + key0] = ds[u];
        }
        if (has2) {
            *(uint4*)&Ks[ko + key1 * 72 + cc1 * 8] = rk1;
            const short* ds = (const short*)&rv1;
#pragma unroll
            for (int u = 0; u < 8; u++) Vs[vo + (cc1 * 8 + u) * 68 + key1] = ds[u];
        }
        unsigned long long mw0 = wq0, mw1 = wq1;
        // prefetch next tile (in flight across barrier)
        rk0 = *(const uint4*)pK0;  pK0 += 61440;
        rv0 = *(const uint4*)pV0;  pV0 += 61440;
        if (has2) { rk1 = *(const uint4*)pK1; rv1 = *(const uint4*)pV1; }
        pK1 += 61440; pV1 += 61440;
        wq0 = *pM0++;
        wq1 = *pM1++;
        __syncthreads();

        const short* KB = &Ks[ko];
        const short* VB = &Vs[vo];
        unsigned lo[2], hi[2];
        lo[0] = (unsigned)(mw0 >> quad);
        hi[0] = (unsigned)(mw0 >> (quad + 32));
        lo[1] = (unsigned)(mw1 >> quad);
        hi[1] = (unsigned)(mw1 >> (quad + 32));

#pragma unroll
        for (int ct = 0; ct < 4; ct++) {
            // QK^T (S^T): A=K frag, B=Q frag, 3 k16 chunks
            f32x4 S[2];
            S[0] = f32x4{0.f, 0.f, 0.f, 0.f};
            S[1] = f32x4{0.f, 0.f, 0.f, 0.f};
#pragma unroll
            for (int kc = 0; kc < 3; kc++) {
                short4v kf = *(const short4v*)&KB[(ct * 16 + l16) * 72 + kc * 16 + quad * 4];
                S[0] = MFMA16(kf, qb[0][kc], S[0]);
                S[1] = MFMA16(kf, qb[1][kc], S[1]);
            }
            // softmax (m == 0): p = exp2(s) * maskbit -> P^T register frag
            short4v pf[2];
#pragma unroll
            for (int qs = 0; qs < 2; qs++) {
                float p0 = __builtin_amdgcn_exp2f(S[qs][0]);
                float p1 = __builtin_amdgcn_exp2f(S[qs][1]);
                float p2 = __builtin_amdgcn_exp2f(S[qs][2]);
                float p3 = __builtin_amdgcn_exp2f(S[qs][3]);
                p0 = ((lo[qs] >> (4 * ct)) & 1u) ? p0 : 0.f;
                p1 = ((lo[qs] >> (4 * ct + 16)) & 1u) ? p1 : 0.f;
                p2 = ((hi[qs] >> (4 * ct)) & 1u) ? p2 : 0.f;
                p3 = ((hi[qs] >> (4 * ct + 16)) & 1u) ? p3 : 0.f;
                unsigned u0 = __float_as_uint(p0) + 0x8000u;
                unsigned u1 = __float_as_uint(p1) + 0x8000u;
                unsigned u2 = __float_as_uint(p2) + 0x8000u;
                unsigned u3 = __float_as_uint(p3) + 0x8000u;
                uint2 pk = make_uint2((u0 >> 16) | (u1 & 0xFFFF0000u),
                                      (u2 >> 16) | (u3 & 0xFFFF0000u));
                pf[qs] = *(short4v*)&pk;
            }
            // PV: O^T[d][q] += V^T . P^T (x16, P from registers)
#pragma unroll
            for (int dt = 0; dt < 3; dt++) {
                short4v vf = *(const short4v*)&VB[(dt * 16 + l16) * 68 + ct * 16 + quad * 4];
                accO[0][dt] = MFMA16(vf, pf[0], accO[0][dt]);
                accO[1][dt] = MFMA16(vf, pf[1], accO[1][dt]);
            }
        }
    }

    // epilogue: unnormalized O (row=d=dt*16+quad*4+r, col=q=l16) + l (d=40)
#pragma unroll
    for (int qs = 0; qs < 2; qs++) {
        int q = q0 + qs * 16 + l16;
        size_t base = ((size_t)(s * NH + h) * LQ + q) * DH;
        float4 f0 = make_float4(accO[qs][0][0], accO[qs][0][1], accO[qs][0][2], accO[qs][0][3]);
        float4 f1 = make_float4(accO[qs][1][0], accO[qs][1][1], accO[qs][1][2], accO[qs][1][3]);
        *(float4*)&Opart[base + quad * 4] = f0;
        *(float4*)&Opart[base + 16 + quad * 4] = f1;
        if (quad < 2) {
            float4 f2 = make_float4(accO[qs][2][0], accO[qs][2][1], accO[qs][2][2], accO[qs][2][3]);
            *(float4*)&Opart[base + 32 + quad * 4] = f2;
        }
        if (quad == 2) l_arr[(size_t)(s * NH + h) * LQ + q] = accO[qs][2][0];
    }
}

// ---------------------------------------------------------------------------
// K4 combine: aob[q][h*40+d] = (sum_s Opart) / (sum_s l), bf16
// ---------------------------------------------------------------------------
__global__ __launch_bounds__(256) void combine(
    const float* __restrict__ Opart, const float* __restrict__ l_arr,
    __hip_bfloat16* __restrict__ aob) {
    int idx = blockIdx.x * 256 + threadIdx.x;   // ((h*4096+q)*5 + dgroup)
    if (idx >= NH * LQ * 5) return;
    int dg = idx % 5;
    int hq = idx / 5;
    int q = hq & (LQ - 1), h = hq >> 12;
    float ls = 0.f;
    float vals[8] = {0, 0, 0, 0, 0, 0, 0, 0};
#pragma unroll
    for (int sp = 0; sp < NSPLIT; sp++) {
        size_t rbase = ((size_t)(sp * NH + h) * LQ + q) * DH + dg * 8;
        float4 a = *(const float4*)&Opart[rbase];
        float4 b = *(const float4*)&Opart[rbase + 4];
        vals[0] += a.x; vals[1] += a.y; vals[2] += a.z; vals[3] += a.w;
        vals[4] += b.x; vals[5] += b.y; vals[6] += b.z; vals[7] += b.w;
        ls += l_arr[(size_t)(sp * NH + h) * LQ + q];
    }
    float inv = 1.f / ls;
    short8 o;
#pragma unroll
    for (int j = 0; j < 8; j++) {
        unsigned u = __float_as_uint(vals[j] * inv) + 0x8000u;
        o[j] = (short)(u >> 16);
    }
    *(short8*)((short*)aob + (size_t)q * CDIM + h * DH + dg * 8) = o;
}

// ---------------------------------------------------------------------------
// K5 out_gemm: out[perm(m)] = aob @ Wot^T + bo (64x64 tile, 4 waves)
// ---------------------------------------------------------------------------
__global__ __launch_bounds__(256) void out_gemm(
    const __hip_bfloat16* __restrict__ Ab, const __hip_bfloat16* __restrict__ Btb,
    float* __restrict__ C, const float* __restrict__ bias) {
    __shared__ short As[64 * 72];
    __shared__ short Bs[64 * 72];
    const short* A  = (const short*)Ab;
    const short* Bt = (const short*)Btb;
    int t = threadIdx.x;
    int wv = t >> 6, lane = t & 63, quad = lane >> 4, l16 = lane & 15;
    int m0 = blockIdx.y * 64, n0 = blockIdx.x * 64;

    f32x4 acc[4];
#pragma unroll
    for (int ct = 0; ct < 4; ct++)
#pragma unroll
        for (int r = 0; r < 4; r++) acc[ct][r] = 0.f;

    for (int k0 = 0; k0 < 320; k0 += 64) {
        uint4 av[2], bv[2];
#pragma unroll
        for (int i = 0; i < 2; i++) {
            int c = t + i * 256;
            int row = c >> 3, kc = (c & 7) * 8;
            av[i] = *(const uint4*)(A + (size_t)(m0 + row) * 320 + k0 + kc);
            bv[i] = *(const uint4*)(Bt + (size_t)(n0 + row) * 320 + k0 + kc);
        }
        __syncthreads();
#pragma unroll
        for (int i = 0; i < 2; i++) {
            int c = t + i * 256;
            *(uint4*)&As[(c >> 3) * 72 + (c & 7) * 8] = av[i];
            *(uint4*)&Bs[(c >> 3) * 72 + (c & 7) * 8] = bv[i];
        }
        __syncthreads();
        short8 a0 = *(const short8*)&As[(wv * 16 + l16) * 72 + quad * 8];
        short8 a1 = *(const short8*)&As[(wv * 16 + l16) * 72 + 32 + quad * 8];
#pragma unroll
        for (int ct = 0; ct < 4; ct++) {
            short8 b0 = *(const short8*)&Bs[(ct * 16 + l16) * 72 + quad * 8];
            short8 b1 = *(const short8*)&Bs[(ct * 16 + l16) * 72 + 32 + quad * 8];
            acc[ct] = MFMA32(a0, b0, acc[ct]);
            acc[ct] = MFMA32(a1, b1, acc[ct]);
        }
        __syncthreads();
    }
#pragma unroll
    for (int ct = 0; ct < 4; ct++)
#pragma unroll
        for (int r = 0; r < 4; r++) {
            int m = m0 + wv * 16 + quad * 4 + r;
            int n = n0 + ct * 16 + l16;
            int rp = (m & 255) * 16 + (m >> 8);
            C[(size_t)rp * CDIM + n] = acc[ct][r] + bias[n];
        }
}

// ---------------------------------------------------------------------------
// kernel_launch (5 launches: prep -> qkv -> flash -> combine -> out)
// ---------------------------------------------------------------------------
extern "C" void kernel_launch(void* const* d_in, const int* in_sizes, int n_in,
                              void* d_out, int out_size, void* d_ws, size_t ws_size,
                              hipStream_t stream) {
    const float* feat = (const float*)d_in[0];
    const int*   mask = (const int*)d_in[1];
    const float* Wq   = (const float*)d_in[2];
    const float* Wk   = (const float*)d_in[3];
    const float* Wv   = (const float*)d_in[4];
    const float* reg  = (const float*)d_in[5];
    const float* Wo   = (const float*)d_in[6];
    const float* bo   = (const float*)d_in[7];
    float* out = (float*)d_out;

    char* p = (char*)d_ws;
    auto alloc = [&](size_t bytes) {
        char* r = p;
        p += (bytes + 255) & ~(size_t)255;
        return r;
    };
    __hip_bfloat16* ctxb = (__hip_bfloat16*)alloc((size_t)LKTX * CDIM * 2);
    __hip_bfloat16* Cb   = (__hip_bfloat16*)alloc((size_t)CBROWS * 960 * 2);
    __hip_bfloat16* Wt   = (__hip_bfloat16*)alloc((size_t)960 * 320 * 2);
    __hip_bfloat16* Wot  = (__hip_bfloat16*)alloc((size_t)320 * 320 * 2);
    unsigned long long* packed =
        (unsigned long long*)alloc(((size_t)LQ * NWORDS + 64) * 8);
    float* Opart = (float*)alloc((size_t)NSPLIT * NH * LQ * DH * 4);
    float* l_arr = (float*)alloc((size_t)NSPLIT * NH * LQ * 4);
    __hip_bfloat16* aob  = (__hip_bfloat16*)alloc((size_t)LQ * CDIM * 2);

    prep<<<17904, 256, 0, stream>>>(feat, reg, Wq, Wk, Wv, Wo, mask, packed,
                                    ctxb, Wt, Wot);
    qkv_gemm<<<dim3(8, 65), 256, 0, stream>>>(ctxb, Wt, Cb);
    flash_attn<<<dim3(32, NH, NSPLIT), 256, 0, stream>>>(Cb, packed, Opart, l_arr);
    combine<<<(NH * LQ * 5 + 255) / 256, 256, 0, stream>>>(Opart, l_arr, aob);
    out_gemm<<<dim3(5, 64), 256, 0, stream>>>(aob, Wot, out, bo);
}